// Round 4
// baseline (239.479 us; speedup 1.0000x reference)
//
#include <hip/hip_runtime.h>

#define WINSZ 2048
#define EMB   64

typedef float f32x4 __attribute__((ext_vector_type(4)));

// ---------------------------------------------------------------------------
// Fused precompute: one block per e (64 blocks).
//   S1[e] = sum_w W1[e,w]   (coalesced row read, values kept in registers)
//   V[w*E + e] = W1[e,w]*W2[e]  (+ W2[e]*(1-S1[e]) at w == WIN-1)
//   block 0 also writes Cconst = sum_e W2[e]*b1[e] + b2
// ---------------------------------------------------------------------------
__global__ __launch_bounds__(256) void nl_precompute(
    const float* __restrict__ W1, const float* __restrict__ b1,
    const float* __restrict__ W2, const float* __restrict__ b2,
    float* __restrict__ V, float* __restrict__ Cconst)
{
    const int e = blockIdx.x;
    const int t = threadIdx.x;

    float vals[WINSZ / 256];          // 8 values per thread, static-indexed
    float s = 0.0f;
    #pragma unroll
    for (int k = 0; k < WINSZ / 256; ++k) {
        const int w = t + k * 256;
        vals[k] = W1[e * WINSZ + w];
        s += vals[k];
    }

    for (int off = 32; off; off >>= 1) s += __shfl_down(s, off, 64);

    __shared__ float sm[4];
    const int lane = t & 63, wid = t >> 6;
    if (lane == 0) sm[wid] = s;
    __syncthreads();

    const float S1 = sm[0] + sm[1] + sm[2] + sm[3];
    const float w2 = W2[e];
    const float ce = w2 * (1.0f - S1);

    #pragma unroll
    for (int k = 0; k < WINSZ / 256; ++k) {
        const int w = t + k * 256;
        float v = vals[k] * w2;
        if (w == WINSZ - 1) v += ce;
        V[w * EMB + e] = v;
    }

    if (e == 0 && t == 0) {
        float acc = b2[0];
        #pragma unroll
        for (int i = 0; i < EMB; ++i) acc = fmaf(W2[i], b1[i], acc);
        *Cconst = acc;
    }
}

// ---------------------------------------------------------------------------
// Main: out[b] = dot(x[b,:,:], V) + C.  FOUR batch rows per block (512
// blocks): each V load from L2 feeds four FMAs (V L2 traffic 512->256 MB,
// load-issue mix 4 x-loads + 1 V-load per 4 vec-FMAs). x streamed
// nontemporal. j unrolled x2 for 10 loads in flight per iteration.
// ---------------------------------------------------------------------------
__global__ __launch_bounds__(256) void nl_main(
    const float* __restrict__ x, const float* __restrict__ V,
    const float* __restrict__ Cconst, float* __restrict__ out)
{
    const int b0 = blockIdx.x * 4;
    const int t  = threadIdx.x;

    constexpr int N4 = (WINSZ * EMB) / 4;   // 32768 float4 per batch row

    const f32x4* __restrict__ xpA = (const f32x4*)(x + (size_t)b0 * (WINSZ * EMB));
    const f32x4* __restrict__ xpB = xpA + N4;
    const f32x4* __restrict__ xpC = xpB + N4;
    const f32x4* __restrict__ xpD = xpC + N4;
    const f32x4* __restrict__ vp  = (const f32x4*)V;

    f32x4 aA0 = {0,0,0,0}, aA1 = {0,0,0,0};
    f32x4 aB0 = {0,0,0,0}, aB1 = {0,0,0,0};
    f32x4 aC0 = {0,0,0,0}, aC1 = {0,0,0,0};
    f32x4 aD0 = {0,0,0,0}, aD1 = {0,0,0,0};

    // 64 outer iterations; 8 x-loads + 2 V-loads + 8 vec-FMAs each.
    for (int j0 = 0; j0 < N4; j0 += 512) {
        const int j = j0 + t;
        const f32x4 xA0 = __builtin_nontemporal_load(xpA + j);
        const f32x4 xA1 = __builtin_nontemporal_load(xpA + j + 256);
        const f32x4 xB0 = __builtin_nontemporal_load(xpB + j);
        const f32x4 xB1 = __builtin_nontemporal_load(xpB + j + 256);
        const f32x4 xC0 = __builtin_nontemporal_load(xpC + j);
        const f32x4 xC1 = __builtin_nontemporal_load(xpC + j + 256);
        const f32x4 xD0 = __builtin_nontemporal_load(xpD + j);
        const f32x4 xD1 = __builtin_nontemporal_load(xpD + j + 256);
        const f32x4 v0  = vp[j];
        const f32x4 v1  = vp[j + 256];
        aA0 += xA0 * v0;  aA1 += xA1 * v1;
        aB0 += xB0 * v0;  aB1 += xB1 * v1;
        aC0 += xC0 * v0;  aC1 += xC1 * v1;
        aD0 += xD0 * v0;  aD1 += xD1 * v1;
    }

    const f32x4 aA = aA0 + aA1;
    const f32x4 aB = aB0 + aB1;
    const f32x4 aC = aC0 + aC1;
    const f32x4 aD = aD0 + aD1;
    float rA = (aA.x + aA.y) + (aA.z + aA.w);
    float rB = (aB.x + aB.y) + (aB.z + aB.w);
    float rC = (aC.x + aC.y) + (aC.z + aC.w);
    float rD = (aD.x + aD.y) + (aD.z + aD.w);

    for (int off = 32; off; off >>= 1) {
        rA += __shfl_down(rA, off, 64);
        rB += __shfl_down(rB, off, 64);
        rC += __shfl_down(rC, off, 64);
        rD += __shfl_down(rD, off, 64);
    }

    __shared__ float smA[4], smB[4], smC[4], smD[4];
    const int lane = t & 63, wid = t >> 6;
    if (lane == 0) { smA[wid] = rA; smB[wid] = rB; smC[wid] = rC; smD[wid] = rD; }
    __syncthreads();

    if (t == 0) {
        const float C = *Cconst;
        out[b0]     = smA[0] + smA[1] + smA[2] + smA[3] + C;
        out[b0 + 1] = smB[0] + smB[1] + smB[2] + smB[3] + C;
        out[b0 + 2] = smC[0] + smC[1] + smC[2] + smC[3] + C;
        out[b0 + 3] = smD[0] + smD[1] + smD[2] + smD[3] + C;
    }
}

// ---------------------------------------------------------------------------
extern "C" void kernel_launch(void* const* d_in, const int* in_sizes, int n_in,
                              void* d_out, int out_size, void* d_ws, size_t ws_size,
                              hipStream_t stream)
{
    const float* x  = (const float*)d_in[0];   // [B, WIN, E]
    const float* W1 = (const float*)d_in[1];   // [E, WIN]
    const float* b1 = (const float*)d_in[2];   // [E]
    const float* W2 = (const float*)d_in[3];   // [E, 1]
    const float* b2 = (const float*)d_in[4];   // [1]
    float* out = (float*)d_out;                // [B]

    float* V  = (float*)d_ws;                  // WIN*E floats
    float* Cc = V + WINSZ * EMB;

    const int B = out_size;                    // 2048

    nl_precompute<<<EMB, 256, 0, stream>>>(W1, b1, W2, b2, V, Cc);
    nl_main<<<B / 4, 256, 0, stream>>>(x, V, Cc, out);
}

// Round 5
// 169.928 us; speedup vs baseline: 1.4093x; 1.4093x over previous
//
#include <hip/hip_runtime.h>

#define WINSZ 2048
#define EMB   64

typedef float f32x4 __attribute__((ext_vector_type(4)));

// ---------------------------------------------------------------------------
// Fused precompute: one block per e (64 blocks).
//   S1[e] = sum_w W1[e,w]   (coalesced row read, values kept in registers)
//   V[w*E + e] = W1[e,w]*W2[e]  (+ W2[e]*(1-S1[e]) at w == WIN-1)
//   block 0 also writes Cconst = sum_e W2[e]*b1[e] + b2
// ---------------------------------------------------------------------------
__global__ __launch_bounds__(256) void nl_precompute(
    const float* __restrict__ W1, const float* __restrict__ b1,
    const float* __restrict__ W2, const float* __restrict__ b2,
    float* __restrict__ V, float* __restrict__ Cconst)
{
    const int e = blockIdx.x;
    const int t = threadIdx.x;

    float vals[WINSZ / 256];          // 8 values per thread, static-indexed
    float s = 0.0f;
    #pragma unroll
    for (int k = 0; k < WINSZ / 256; ++k) {
        const int w = t + k * 256;
        vals[k] = W1[e * WINSZ + w];
        s += vals[k];
    }

    for (int off = 32; off; off >>= 1) s += __shfl_down(s, off, 64);

    __shared__ float sm[4];
    const int lane = t & 63, wid = t >> 6;
    if (lane == 0) sm[wid] = s;
    __syncthreads();

    const float S1 = sm[0] + sm[1] + sm[2] + sm[3];
    const float w2 = W2[e];
    const float ce = w2 * (1.0f - S1);

    #pragma unroll
    for (int k = 0; k < WINSZ / 256; ++k) {
        const int w = t + k * 256;
        float v = vals[k] * w2;
        if (w == WINSZ - 1) v += ce;
        V[w * EMB + e] = v;
    }

    if (e == 0 && t == 0) {
        float acc = b2[0];
        #pragma unroll
        for (int i = 0; i < EMB; ++i) acc = fmaf(W2[i], b1[i], acc);
        *Cconst = acc;
    }
}

// ---------------------------------------------------------------------------
// Main: out[b] = dot(x[b,:,:], V) + C.  TWO batch rows per block (1024
// blocks = 4 blocks/CU = 16 waves/CU — occupancy is the latency-hiding
// resource; 4 rows/block (512 blocks) measured -41%). Each V load from L2
// feeds two FMAs. x streamed nontemporal so V stays L2-resident.
// ---------------------------------------------------------------------------
__global__ __launch_bounds__(256) void nl_main(
    const float* __restrict__ x, const float* __restrict__ V,
    const float* __restrict__ Cconst, float* __restrict__ out)
{
    const int b0 = blockIdx.x * 2;
    const int t  = threadIdx.x;

    constexpr int N4 = (WINSZ * EMB) / 4;   // 32768 float4 per batch row

    const f32x4* __restrict__ xp0 = (const f32x4*)(x + (size_t)b0 * (WINSZ * EMB));
    const f32x4* __restrict__ xp1 = xp0 + N4;
    const f32x4* __restrict__ vp  = (const f32x4*)V;

    f32x4 a00 = {0,0,0,0}, a01 = {0,0,0,0};
    f32x4 a10 = {0,0,0,0}, a11 = {0,0,0,0};

    // 64 outer iterations; 4 x-loads + 2 V-loads + 4 vec-FMAs each.
    for (int j0 = 0; j0 < N4; j0 += 512) {
        const int j = j0 + t;
        const f32x4 xA0 = __builtin_nontemporal_load(xp0 + j);
        const f32x4 xA1 = __builtin_nontemporal_load(xp0 + j + 256);
        const f32x4 xB0 = __builtin_nontemporal_load(xp1 + j);
        const f32x4 xB1 = __builtin_nontemporal_load(xp1 + j + 256);
        const f32x4 v0  = vp[j];
        const f32x4 v1  = vp[j + 256];
        a00 += xA0 * v0;
        a01 += xA1 * v1;
        a10 += xB0 * v0;
        a11 += xB1 * v1;
    }

    const f32x4 aA = a00 + a01;
    const f32x4 aB = a10 + a11;
    float r0 = (aA.x + aA.y) + (aA.z + aA.w);
    float r1 = (aB.x + aB.y) + (aB.z + aB.w);

    for (int off = 32; off; off >>= 1) {
        r0 += __shfl_down(r0, off, 64);
        r1 += __shfl_down(r1, off, 64);
    }

    __shared__ float smA[4], smB[4];
    const int lane = t & 63, wid = t >> 6;
    if (lane == 0) { smA[wid] = r0; smB[wid] = r1; }
    __syncthreads();

    if (t == 0) {
        const float C = *Cconst;
        out[b0]     = smA[0] + smA[1] + smA[2] + smA[3] + C;
        out[b0 + 1] = smB[0] + smB[1] + smB[2] + smB[3] + C;
    }
}

// ---------------------------------------------------------------------------
extern "C" void kernel_launch(void* const* d_in, const int* in_sizes, int n_in,
                              void* d_out, int out_size, void* d_ws, size_t ws_size,
                              hipStream_t stream)
{
    const float* x  = (const float*)d_in[0];   // [B, WIN, E]
    const float* W1 = (const float*)d_in[1];   // [E, WIN]
    const float* b1 = (const float*)d_in[2];   // [E]
    const float* W2 = (const float*)d_in[3];   // [E, 1]
    const float* b2 = (const float*)d_in[4];   // [1]
    float* out = (float*)d_out;                // [B]

    float* V  = (float*)d_ws;                  // WIN*E floats
    float* Cc = V + WINSZ * EMB;

    const int B = out_size;                    // 2048

    nl_precompute<<<EMB, 256, 0, stream>>>(W1, b1, W2, b2, V, Cc);
    nl_main<<<B / 2, 256, 0, stream>>>(x, V, Cc, out);
}